// Round 1
// baseline (1246.075 us; speedup 1.0000x reference)
//
#include <hip/hip_runtime.h>
#include <hip/hip_bf16.h>

#define BTOT 16384
typedef unsigned short u16;

__device__ __forceinline__ u16 f2b(float f) {
  unsigned int i = __float_as_uint(f);
  return (u16)((i + 0x7FFFu + ((i >> 16) & 1u)) >> 16);
}
__device__ __forceinline__ float b2f(u16 u) {
  return __uint_as_float(((unsigned int)u) << 16);
}

// lookup tables (file-scope device const to avoid scratch from runtime indexing)
__device__ const int c_mb[8][3]  = {{0,0,0},{1,0,0},{1,0,0},{1,0,0},{1,0,0},{1,0,0},{1,0,0},{1,1,0}};
__device__ const int c_mj[8][3]  = {{0,1,5},{0,3,7},{5,7,8},{1,2,0},{3,4,0},{8,9,0},{10,11,0},{6,7,10}};
__device__ const int c_opof[8]   = {0,1,1,2,2,2,2,3};
__device__ const int c_jmap[12]  = {0,1,3,4,8,9,2,7,5,6,10,11}; // out pos i <- res joint jmap[i]
__device__ const int c_vj[4]     = {2,4,9,11};

// ---------------- prep: transpose weights (WT[c][d] = W[d][c]) + zero stats ----------
__global__ __launch_bounds__(256) void k_prep(
    const float* __restrict__ wev, const float* __restrict__ wve,
    const float* __restrict__ w1, const float* __restrict__ w2,
    const float* __restrict__ w3, const float* __restrict__ w4,
    float* __restrict__ wt, float* __restrict__ stats)
{
  int id = blockIdx.x * 256 + threadIdx.x;
  if (blockIdx.x == 0) {
    for (int i = threadIdx.x; i < 1536; i += 256) stats[i] = 0.f;
  }
  const float* src; int base, K;
  if (id < 32768)       { src = wev; base = 0;      K = 256; }
  else if (id < 65536)  { src = wve; base = 32768;  K = 256; }
  else if (id < 114688) { src = w1;  base = 65536;  K = 384; }
  else if (id < 163840) { src = w2;  base = 114688; K = 384; }
  else if (id < 196608) { src = w3;  base = 163840; K = 256; }
  else if (id < 245760) { src = w4;  base = 196608; K = 384; }
  else return;
  int local = id - base;
  int c = local >> 7, d = local & 127;
  wt[base + local] = src[d * K + c];
}

// ---------------- stage1: y_ev/y_ve pre-BN GEMMs + stats ----------------------------
// block: 256 thr, processes 16 b in 4 tiles of 4.
// thread: bb = tid>>6 (batch within tile), ch = (tid&63)>>5 (c-half), dt = (tid&31)*4
__global__ __launch_bounds__(256) void k_stage1(
    const float* __restrict__ gout, const float* __restrict__ eout,
    const float* __restrict__ evs, const float* __restrict__ ves,
    const float* __restrict__ wtev, const float* __restrict__ wtve,
    u16* __restrict__ y_ev, u16* __restrict__ y_ve, float* __restrict__ stats)
{
  __shared__ float s_g[4 * 1536];
  __shared__ float s_e[4 * 1536];
  __shared__ float s_m[4 * 1536];
  __shared__ float s_sh[288];
  const int tid = threadIdx.x;
  for (int i = tid; i < 288; i += 256) s_sh[i] = (i < 144) ? evs[i] : ves[i - 144];

  const int bb = tid >> 6;
  const int l  = tid & 63;
  const int ch = l >> 5;
  const int dt = (l & 31) * 4;

  float sev[4] = {0,0,0,0}, qev[4] = {0,0,0,0};
  float sve[4] = {0,0,0,0}, qve[4] = {0,0,0,0};

  for (int t = 0; t < 4; ++t) {
    const int b0 = blockIdx.x * 16 + t * 4;
    __syncthreads();
    {
      const float4* gs = (const float4*)(gout + (size_t)b0 * 1536);
      const float4* es = (const float4*)(eout + (size_t)b0 * 1536);
      float4* gd = (float4*)s_g; float4* ed = (float4*)s_e;
      #pragma unroll
      for (int k = 0; k < 6; ++k) { int i = tid + k * 256; gd[i] = gs[i]; ed[i] = es[i]; }
    }
    __syncthreads();
    // ev_g -> s_m
    for (int bbi = 0; bbi < 4; ++bbi) {
      #pragma unroll
      for (int k = 0; k < 6; ++k) {
        int i = tid + k * 256;
        int n = i >> 7, d = i & 127;
        float acc = 0.f;
        #pragma unroll
        for (int j = 0; j < 12; ++j) acc = fmaf(s_sh[n*12 + j], s_g[bbi*1536 + j*128 + d], acc);
        s_m[bbi*1536 + i] = acc;
      }
    }
    __syncthreads();
    // matmul EV: X = [eout | evg]
    {
      float acc[12][4];
      #pragma unroll
      for (int n = 0; n < 12; ++n) { acc[n][0]=0.f; acc[n][1]=0.f; acc[n][2]=0.f; acc[n][3]=0.f; }
      const float* xp = ch ? (s_m + bb*1536) : (s_e + bb*1536);
      const float* wp = wtev + ch * 16384 + dt;
      for (int cc = 0; cc < 128; ++cc) {
        float4 w4 = *(const float4*)(wp + (cc << 7));
        #pragma unroll
        for (int n = 0; n < 12; ++n) {
          float x = xp[(n << 7) + cc];
          acc[n][0] = fmaf(x, w4.x, acc[n][0]);
          acc[n][1] = fmaf(x, w4.y, acc[n][1]);
          acc[n][2] = fmaf(x, w4.z, acc[n][2]);
          acc[n][3] = fmaf(x, w4.w, acc[n][3]);
        }
      }
      #pragma unroll
      for (int n = 0; n < 12; ++n)
        #pragma unroll
        for (int k = 0; k < 4; ++k)
          acc[n][k] += __shfl_xor(acc[n][k], 32);
      if (ch == 0) {
        #pragma unroll
        for (int n = 0; n < 12; ++n) {
          ushort4 pk = make_ushort4(f2b(acc[n][0]), f2b(acc[n][1]), f2b(acc[n][2]), f2b(acc[n][3]));
          *(ushort4*)&y_ev[((size_t)(b0 + bb) * 12 + n) * 128 + dt] = pk;
          #pragma unroll
          for (int k = 0; k < 4; ++k) { sev[k] += acc[n][k]; qev[k] += acc[n][k]*acc[n][k]; }
        }
      }
    }
    __syncthreads();
    // ve_g -> s_m
    for (int bbi = 0; bbi < 4; ++bbi) {
      #pragma unroll
      for (int k = 0; k < 6; ++k) {
        int i = tid + k * 256;
        int n = i >> 7, d = i & 127;
        float acc = 0.f;
        #pragma unroll
        for (int j = 0; j < 12; ++j) acc = fmaf(s_sh[144 + n*12 + j], s_g[bbi*1536 + j*128 + d], acc);
        s_m[bbi*1536 + i] = acc;
      }
    }
    __syncthreads();
    // matmul VE: X = [veg | eout]
    {
      float acc[12][4];
      #pragma unroll
      for (int n = 0; n < 12; ++n) { acc[n][0]=0.f; acc[n][1]=0.f; acc[n][2]=0.f; acc[n][3]=0.f; }
      const float* xp = ch ? (s_e + bb*1536) : (s_m + bb*1536);
      const float* wp = wtve + ch * 16384 + dt;
      for (int cc = 0; cc < 128; ++cc) {
        float4 w4 = *(const float4*)(wp + (cc << 7));
        #pragma unroll
        for (int n = 0; n < 12; ++n) {
          float x = xp[(n << 7) + cc];
          acc[n][0] = fmaf(x, w4.x, acc[n][0]);
          acc[n][1] = fmaf(x, w4.y, acc[n][1]);
          acc[n][2] = fmaf(x, w4.z, acc[n][2]);
          acc[n][3] = fmaf(x, w4.w, acc[n][3]);
        }
      }
      #pragma unroll
      for (int n = 0; n < 12; ++n)
        #pragma unroll
        for (int k = 0; k < 4; ++k)
          acc[n][k] += __shfl_xor(acc[n][k], 32);
      if (ch == 0) {
        #pragma unroll
        for (int n = 0; n < 12; ++n) {
          ushort4 pk = make_ushort4(f2b(acc[n][0]), f2b(acc[n][1]), f2b(acc[n][2]), f2b(acc[n][3]));
          *(ushort4*)&y_ve[((size_t)(b0 + bb) * 12 + n) * 128 + dt] = pk;
          #pragma unroll
          for (int k = 0; k < 4; ++k) { sve[k] += acc[n][k]; qve[k] += acc[n][k]*acc[n][k]; }
        }
      }
    }
  }
  if (ch == 0) {
    #pragma unroll
    for (int k = 0; k < 4; ++k) {
      atomicAdd(&stats[dt + k],        sev[k]);
      atomicAdd(&stats[128 + dt + k],  qev[k]);
      atomicAdd(&stats[256 + dt + k],  sve[k]);
      atomicAdd(&stats[384 + dt + k],  qve[k]);
    }
  }
}

// ---------------- finalize1: ev/ve BN -> affine (a, c) -----------------------------
__global__ void k_fin1(const float* __restrict__ stats, float* __restrict__ scale,
                       const float* __restrict__ gev, const float* __restrict__ bev,
                       const float* __restrict__ gve, const float* __restrict__ bve)
{
  int tid = threadIdx.x;
  int m = tid >> 7, d = tid & 127;
  float cnt = (float)(BTOT * 12);
  float sum = stats[m*256 + d], sq = stats[m*256 + 128 + d];
  float mean = sum / cnt;
  float var = sq / cnt - mean * mean;
  float rs = rsqrtf(var + 1e-5f);
  float g = m ? gve[d] : gev[d];
  float b = m ? bve[d] : bev[d];
  float a = g * rs;
  scale[m*256 + d] = a;
  scale[m*256 + 128 + d] = b - mean * a;
}

// ---------------- stage2: op1..op4 pre-BN GEMMs + stats ----------------------------
// block: 256 thr = 8 rows x 32 lanes (4 d each); 4 tiles of 8 b => 32 b per block
__global__ __launch_bounds__(256) void k_stage2(
    const u16* __restrict__ y_ev, const u16* __restrict__ y_ve,
    const float* __restrict__ scale,
    const float* __restrict__ wt1, const float* __restrict__ wt2,
    const float* __restrict__ wt3, const float* __restrict__ wt4,
    u16* __restrict__ y_op, float* __restrict__ stats)
{
  __shared__ float s_f[24576]; // [8 b][2 buf][12 n][128 d]
  const int tid = threadIdx.x;
  const int r  = tid >> 5;
  const int dt = (tid & 31) * 4;
  const int Kr = (r >= 3 && r <= 6) ? 256 : 384;
  const float* wr = (r == 0) ? wt1 : (r <= 2) ? wt2 : (r <= 6) ? wt3 : wt4;
  const int xo0 = c_mb[r][0]*1536 + c_mj[r][0]*128;
  const int xo1 = c_mb[r][1]*1536 + c_mj[r][1]*128;
  const int xo2 = c_mb[r][2]*1536 + c_mj[r][2]*128;
  const int o = c_opof[r];
  float ssum[4] = {0,0,0,0}, ssq[4] = {0,0,0,0};

  for (int t = 0; t < 4; ++t) {
    const int b0 = blockIdx.x * 32 + t * 8;
    __syncthreads();
    // ef (BN+relu applied on load)
    for (int i = tid; i < 3072; i += 256) {
      int e4 = i * 4;
      int bbi = e4 / 1536;
      int rem = e4 - bbi * 1536;
      int d = rem & 127;
      ushort4 u = *(const ushort4*)&y_ev[(size_t)b0 * 1536 + e4];
      float4 a4 = *(const float4*)&scale[d];
      float4 c4 = *(const float4*)&scale[128 + d];
      float4 v;
      v.x = fmaxf(fmaf(b2f(u.x), a4.x, c4.x), 0.f);
      v.y = fmaxf(fmaf(b2f(u.y), a4.y, c4.y), 0.f);
      v.z = fmaxf(fmaf(b2f(u.z), a4.z, c4.z), 0.f);
      v.w = fmaxf(fmaf(b2f(u.w), a4.w, c4.w), 0.f);
      *(float4*)&s_f[bbi*3072 + rem] = v;
    }
    // vf
    for (int i = tid; i < 3072; i += 256) {
      int e4 = i * 4;
      int bbi = e4 / 1536;
      int rem = e4 - bbi * 1536;
      int d = rem & 127;
      ushort4 u = *(const ushort4*)&y_ve[(size_t)b0 * 1536 + e4];
      float4 a4 = *(const float4*)&scale[256 + d];
      float4 c4 = *(const float4*)&scale[384 + d];
      float4 v;
      v.x = fmaxf(fmaf(b2f(u.x), a4.x, c4.x), 0.f);
      v.y = fmaxf(fmaf(b2f(u.y), a4.y, c4.y), 0.f);
      v.z = fmaxf(fmaf(b2f(u.z), a4.z, c4.z), 0.f);
      v.w = fmaxf(fmaf(b2f(u.w), a4.w, c4.w), 0.f);
      *(float4*)&s_f[bbi*3072 + 1536 + rem] = v;
    }
    __syncthreads();
    float acc[8][4];
    #pragma unroll
    for (int bbi = 0; bbi < 8; ++bbi) { acc[bbi][0]=0.f; acc[bbi][1]=0.f; acc[bbi][2]=0.f; acc[bbi][3]=0.f; }
    auto do_chunk = [&](const float* xb, const float* wp) {
      for (int cc = 0; cc < 128; ++cc) {
        float4 w4 = *(const float4*)(wp + (cc << 7));
        #pragma unroll
        for (int bbi = 0; bbi < 8; ++bbi) {
          float x = xb[bbi*3072 + cc];
          acc[bbi][0] = fmaf(x, w4.x, acc[bbi][0]);
          acc[bbi][1] = fmaf(x, w4.y, acc[bbi][1]);
          acc[bbi][2] = fmaf(x, w4.z, acc[bbi][2]);
          acc[bbi][3] = fmaf(x, w4.w, acc[bbi][3]);
        }
      }
    };
    do_chunk(s_f + xo0, wr + dt);
    do_chunk(s_f + xo1, wr + 16384 + dt);
    if (Kr == 384) do_chunk(s_f + xo2, wr + 32768 + dt);
    #pragma unroll
    for (int bbi = 0; bbi < 8; ++bbi) {
      ushort4 pk = make_ushort4(f2b(acc[bbi][0]), f2b(acc[bbi][1]), f2b(acc[bbi][2]), f2b(acc[bbi][3]));
      *(ushort4*)&y_op[((size_t)(b0 + bbi) * 8 + r) * 128 + dt] = pk;
      #pragma unroll
      for (int k = 0; k < 4; ++k) { ssum[k] += acc[bbi][k]; ssq[k] += acc[bbi][k]*acc[bbi][k]; }
    }
  }
  #pragma unroll
  for (int k = 0; k < 4; ++k) {
    atomicAdd(&stats[512 + o*256 + dt + k],       ssum[k]);
    atomicAdd(&stats[512 + o*256 + 128 + dt + k], ssq[k]);
  }
}

// ---------------- finalize2: op BN -> affine ---------------------------------------
__global__ void k_fin2(const float* __restrict__ stats, float* __restrict__ scale,
    const float* __restrict__ g1, const float* __restrict__ b1,
    const float* __restrict__ g2, const float* __restrict__ b2,
    const float* __restrict__ g3, const float* __restrict__ b3,
    const float* __restrict__ g4, const float* __restrict__ b4)
{
  int tid = threadIdx.x; // 512 threads
  int o = tid >> 7, d = tid & 127;
  float cnt = (o == 0 || o == 3) ? 16384.f : (o == 1 ? 32768.f : 65536.f);
  float sum = stats[512 + o*256 + d], sq = stats[512 + o*256 + 128 + d];
  float mean = sum / cnt, var = sq / cnt - mean * mean;
  float rs = rsqrtf(var + 1e-5f);
  const float* gp = (o == 0) ? g1 : (o == 1) ? g2 : (o == 2) ? g3 : g4;
  const float* bp = (o == 0) ? b1 : (o == 1) ? b2 : (o == 2) ? b3 : b4;
  float a = gp[d] * rs;
  scale[512 + o*256 + d] = a;
  scale[512 + o*256 + 128 + d] = bp[d] - mean * a;
}

// ---------------- stage3: BN-apply + permute + residual relu -----------------------
__global__ __launch_bounds__(256) void k_stage3(
    const u16* __restrict__ y_op, const u16* __restrict__ y_ve,
    const float* __restrict__ scale, const float* __restrict__ gout,
    float* __restrict__ out)
{
  const int stride = gridDim.x * 256;
  const int total = BTOT * 12 * 32;
  for (int id = blockIdx.x * 256 + threadIdx.x; id < total; id += stride) {
    int b = id / 384;
    int rem = id - b * 384;
    int i = rem >> 5;
    int d4 = (rem & 31) * 4;
    int j = c_jmap[i];
    float4 v;
    if (j < 8) {
      ushort4 u = *(const ushort4*)&y_op[((size_t)b * 8 + j) * 128 + d4];
      int o = c_opof[j];
      float4 a4 = *(const float4*)&scale[512 + o*256 + d4];
      float4 c4 = *(const float4*)&scale[512 + o*256 + 128 + d4];
      v.x = fmaf(b2f(u.x), a4.x, c4.x);
      v.y = fmaf(b2f(u.y), a4.y, c4.y);
      v.z = fmaf(b2f(u.z), a4.z, c4.z);
      v.w = fmaf(b2f(u.w), a4.w, c4.w);
    } else {
      int jv = c_vj[j - 8];
      ushort4 u = *(const ushort4*)&y_ve[((size_t)b * 12 + jv) * 128 + d4];
      float4 a4 = *(const float4*)&scale[256 + d4];
      float4 c4 = *(const float4*)&scale[384 + d4];
      v.x = fmaxf(fmaf(b2f(u.x), a4.x, c4.x), 0.f);
      v.y = fmaxf(fmaf(b2f(u.y), a4.y, c4.y), 0.f);
      v.z = fmaxf(fmaf(b2f(u.z), a4.z, c4.z), 0.f);
      v.w = fmaxf(fmaf(b2f(u.w), a4.w, c4.w), 0.f);
    }
    float4 g4 = *(const float4*)&gout[((size_t)b * 12 + i) * 128 + d4];
    float4 r4;
    r4.x = fmaxf(g4.x + v.x, 0.f);
    r4.y = fmaxf(g4.y + v.y, 0.f);
    r4.z = fmaxf(g4.z + v.z, 0.f);
    r4.w = fmaxf(g4.w + v.w, 0.f);
    *(float4*)&out[((size_t)b * 12 + i) * 128 + d4] = r4;
  }
}

extern "C" void kernel_launch(void* const* d_in, const int* in_sizes, int n_in,
                              void* d_out, int out_size, void* d_ws, size_t ws_size,
                              hipStream_t stream) {
  (void)in_sizes; (void)n_in; (void)out_size; (void)ws_size;
  const float* gout = (const float*)d_in[0];
  const float* eout = (const float*)d_in[1];
  const float* evs  = (const float*)d_in[2];
  const float* ves  = (const float*)d_in[3];
  const float* wev  = (const float*)d_in[4];
  const float* wve  = (const float*)d_in[5];
  const float* w1   = (const float*)d_in[6];
  const float* w2   = (const float*)d_in[7];
  const float* w3   = (const float*)d_in[8];
  const float* w4   = (const float*)d_in[9];
  const float* g_ev = (const float*)d_in[10]; const float* b_ev = (const float*)d_in[11];
  const float* g_ve = (const float*)d_in[12]; const float* b_ve = (const float*)d_in[13];
  const float* g_1  = (const float*)d_in[14]; const float* b_1  = (const float*)d_in[15];
  const float* g_2  = (const float*)d_in[16]; const float* b_2  = (const float*)d_in[17];
  const float* g_3  = (const float*)d_in[18]; const float* b_3  = (const float*)d_in[19];
  const float* g_4  = (const float*)d_in[20]; const float* b_4  = (const float*)d_in[21];

  char* ws = (char*)d_ws;
  u16*   y_ev  = (u16*)ws;                              // 25165824 bf16
  u16*   y_ve  = (u16*)(ws + 50331648);                 // 25165824 bf16
  u16*   y_op  = (u16*)(ws + 100663296);                // 16777216 bf16
  float* stats = (float*)(ws + 134217728);              // 1536 f32
  float* scale = (float*)(ws + 134223872);              // 1536 f32
  float* wt    = (float*)(ws + 134230016);              // 245760 f32

  k_prep<<<960, 256, 0, stream>>>(wev, wve, w1, w2, w3, w4, wt, stats);
  k_stage1<<<1024, 256, 0, stream>>>(gout, eout, evs, ves, wt, wt + 32768, y_ev, y_ve, stats);
  k_fin1<<<1, 256, 0, stream>>>(stats, scale, g_ev, b_ev, g_ve, b_ve);
  k_stage2<<<512, 256, 0, stream>>>(y_ev, y_ve, scale, wt + 65536, wt + 114688, wt + 163840, wt + 196608, y_op, stats);
  k_fin2<<<1, 512, 0, stream>>>(stats, scale, g_1, b_1, g_2, b_2, g_3, b_3, g_4, b_4);
  k_stage3<<<4096, 256, 0, stream>>>(y_op, y_ve, scale, gout, (float*)d_out);
}

// Round 3
// 329.595 us; speedup vs baseline: 3.7806x; 3.7806x over previous
//
#include <hip/hip_runtime.h>
#include <hip/hip_bf16.h>

#define BTOT 16384
typedef unsigned short u16;
typedef __attribute__((ext_vector_type(8))) short bf16x8;
typedef __attribute__((ext_vector_type(8))) unsigned short u16x8;
typedef __attribute__((ext_vector_type(4))) float f32x4;

#define MFMA16(a, b, c) __builtin_amdgcn_mfma_f32_16x16x32_bf16(a, b, c, 0, 0, 0)

__device__ __forceinline__ u16 f2b(float f) {
  unsigned int i = __float_as_uint(f);
  return (u16)((i + 0x7FFFu + ((i >> 16) & 1u)) >> 16);
}
__device__ __forceinline__ float b2f(u16 u) {
  return __uint_as_float(((unsigned int)u) << 16);
}

__device__ const int c_mb[8][3]  = {{0,0,0},{1,0,0},{1,0,0},{1,0,0},{1,0,0},{1,0,0},{1,0,0},{1,1,0}};
__device__ const int c_mj[8][3]  = {{0,1,5},{0,3,7},{5,7,8},{1,2,0},{3,4,0},{8,9,0},{10,11,0},{6,7,10}};
__device__ const int c_opof[8]   = {0,1,1,2,2,2,2,3};
__device__ const int c_jmap[12]  = {0,1,3,4,8,9,2,7,5,6,10,11};
__device__ const int c_vj[4]     = {2,4,9,11};

// ---------------- prep: convert all W to bf16 (layout [d][c] == [n][k]) -----------
__global__ __launch_bounds__(256) void k_prep(
    const float* __restrict__ wev, const float* __restrict__ wve,
    const float* __restrict__ w1, const float* __restrict__ w2,
    const float* __restrict__ w3, const float* __restrict__ w4,
    u16* __restrict__ wb)
{
  int id = blockIdx.x * 256 + threadIdx.x;
  const float* src; int base;
  if (id < 32768)       { src = wev; base = 0; }
  else if (id < 65536)  { src = wve; base = 32768; }
  else if (id < 114688) { src = w1;  base = 65536; }
  else if (id < 163840) { src = w2;  base = 114688; }
  else if (id < 196608) { src = w3;  base = 163840; }
  else if (id < 245760) { src = w4;  base = 196608; }
  else return;
  wb[id] = f2b(src[id - base]);
}

// ---------------- stage1: MFMA GEMMs for y_ev / y_ve + stat partials ---------------
// block: 256 thr = 4 waves (wm in {0,1} x wn in {0,1}); 8 batches -> M=96 rows, N=128, K=256
__global__ __launch_bounds__(256, 2) void k_stage1(
    const float* __restrict__ gout, const float* __restrict__ eout,
    const float* __restrict__ evs, const float* __restrict__ ves,
    const u16* __restrict__ wb_ev, const u16* __restrict__ wb_ve,
    u16* __restrict__ y_ev, u16* __restrict__ y_ve, float* __restrict__ part1)
{
  __shared__ __align__(16) u16 s_e[96 * 128];   // X half: eout (bf16, swizzled)
  __shared__ __align__(16) u16 s_m[96 * 128];   // X half: mix  (bf16, swizzled)
  __shared__ __align__(16) u16 s_w[128 * 64];   // W chunk [n][k64] (bf16, swizzled)
  __shared__ float s_sh[288];
  __shared__ float s_red[512];
  char* se = (char*)s_e; char* sm = (char*)s_m; char* sw = (char*)s_w;

  const int tid = threadIdx.x;
  const int l  = tid & 63, wv = tid >> 6;
  const int wm = wv >> 1, wn = wv & 1;
  const int b0 = blockIdx.x * 8;

  // FIX (round 2 bug): block has 256 threads, table has 288 entries -> must loop.
  for (int i = tid; i < 288; i += 256) s_sh[i] = (i < 144) ? evs[i] : ves[i - 144];
  s_red[tid] = 0.f; s_red[tid + 256] = 0.f;
  __syncthreads();

  // ---- stage eout (convert) + compute ev mix in registers ----
  const int bb = tid >> 5;
  const int d4 = (tid & 31) * 4;
  {
    float mev[12][4];
    #pragma unroll
    for (int n = 0; n < 12; ++n)
      #pragma unroll
      for (int q = 0; q < 4; ++q) mev[n][q] = 0.f;

    #pragma unroll
    for (int j = 0; j < 12; ++j) {
      float4 g4 = *(const float4*)&gout[((size_t)(b0 + bb) * 12 + j) * 128 + d4];
      float4 e4 = *(const float4*)&eout[((size_t)(b0 + bb) * 12 + j) * 128 + d4];
      int row = bb * 12 + j;
      ushort4 ep = make_ushort4(f2b(e4.x), f2b(e4.y), f2b(e4.z), f2b(e4.w));
      *(ushort4*)(se + row * 256 + ((d4 * 2) ^ ((row & 7) << 4))) = ep;
      #pragma unroll
      for (int n = 0; n < 12; ++n) {
        float we = s_sh[n * 12 + j];
        mev[n][0] = fmaf(we, g4.x, mev[n][0]); mev[n][1] = fmaf(we, g4.y, mev[n][1]);
        mev[n][2] = fmaf(we, g4.z, mev[n][2]); mev[n][3] = fmaf(we, g4.w, mev[n][3]);
      }
    }
    #pragma unroll
    for (int n = 0; n < 12; ++n) {
      int row = bb * 12 + n;
      ushort4 mp = make_ushort4(f2b(mev[n][0]), f2b(mev[n][1]), f2b(mev[n][2]), f2b(mev[n][3]));
      *(ushort4*)(sm + row * 256 + ((d4 * 2) ^ ((row & 7) << 4))) = mp;
    }
  }
  __syncthreads();

  float sE[4] = {0,0,0,0}, qE[4] = {0,0,0,0}, sV[4] = {0,0,0,0}, qV[4] = {0,0,0,0};

  auto run_pass = [&](const u16* wmat, const char* x0, const char* x1,
                      u16* yout, char* dump, int which) {
    f32x4 acc[3][4];
    #pragma unroll
    for (int mi = 0; mi < 3; ++mi)
      #pragma unroll
      for (int ni = 0; ni < 4; ++ni) acc[mi][ni] = (f32x4){0.f, 0.f, 0.f, 0.f};

    for (int c = 0; c < 4; ++c) {
      #pragma unroll
      for (int q = 0; q < 4; ++q) {
        int i = tid + q * 256;
        int n = i >> 3, ko = (i & 7) * 8;
        u16x8 w8 = *(const u16x8*)&wmat[n * 256 + c * 64 + ko];
        *(u16x8*)(sw + n * 128 + ((ko * 2) ^ ((n & 7) << 4))) = w8;
      }
      __syncthreads();
      const char* xb = (c < 2) ? x0 : x1;
      #pragma unroll
      for (int kt = 0; kt < 2; ++kt) {
        int kb = (((c & 1) * 64 + kt * 32) + ((l >> 4) * 8)) * 2;
        int kw = ((kt * 32) + ((l >> 4) * 8)) * 2;
        bf16x8 a[3], bq[4];
        #pragma unroll
        for (int mi = 0; mi < 3; ++mi) {
          int row = (wm * 3 + mi) * 16 + (l & 15);
          a[mi] = *(const bf16x8*)(xb + row * 256 + (kb ^ ((row & 7) << 4)));
        }
        #pragma unroll
        for (int ni = 0; ni < 4; ++ni) {
          int n = (wn * 4 + ni) * 16 + (l & 15);
          bq[ni] = *(const bf16x8*)(sw + n * 128 + (kw ^ ((n & 7) << 4)));
        }
        #pragma unroll
        for (int mi = 0; mi < 3; ++mi)
          #pragma unroll
          for (int ni = 0; ni < 4; ++ni)
            acc[mi][ni] = MFMA16(a[mi], bq[ni], acc[mi][ni]);
      }
      __syncthreads();
    }
    // stats + dump to LDS (bf16, swizzled)
    #pragma unroll
    for (int mi = 0; mi < 3; ++mi)
      #pragma unroll
      for (int ni = 0; ni < 4; ++ni)
        #pragma unroll
        for (int q = 0; q < 4; ++q) {
          float v = acc[mi][ni][q];
          if (which == 0) { sE[ni] += v; qE[ni] += v * v; }
          else            { sV[ni] += v; qV[ni] += v * v; }
          int row = (wm * 3 + mi) * 16 + (l >> 4) * 4 + q;
          int cb = ((wn * 4 + ni) * 16 + (l & 15)) * 2;
          *(u16*)(dump + row * 256 + (cb ^ ((row & 7) << 4))) = f2b(v);
        }
    __syncthreads();
    // coalesced store 96x128 bf16
    #pragma unroll
    for (int q = 0; q < 6; ++q) {
      int i = tid + q * 256;
      int row = i >> 4, cb = (i & 15) * 16;
      u16x8 v = *(const u16x8*)(dump + row * 256 + (cb ^ ((row & 7) << 4)));
      *(u16x8*)&yout[(size_t)(b0 * 12 + row) * 128 + (i & 15) * 8] = v;
    }
    __syncthreads();
  };

  // EV: X = [eout | ev_g]; dump into s_m (consumed, rewritten after)
  run_pass(wb_ev, se, sm, y_ev, sm, 0);

  // ---- compute ve mix now (re-read gout, L2-hot) -> s_m ----
  {
    float mve[12][4];
    #pragma unroll
    for (int n = 0; n < 12; ++n)
      #pragma unroll
      for (int q = 0; q < 4; ++q) mve[n][q] = 0.f;
    #pragma unroll
    for (int j = 0; j < 12; ++j) {
      float4 g4 = *(const float4*)&gout[((size_t)(b0 + bb) * 12 + j) * 128 + d4];
      #pragma unroll
      for (int n = 0; n < 12; ++n) {
        float wq = s_sh[144 + n * 12 + j];
        mve[n][0] = fmaf(wq, g4.x, mve[n][0]); mve[n][1] = fmaf(wq, g4.y, mve[n][1]);
        mve[n][2] = fmaf(wq, g4.z, mve[n][2]); mve[n][3] = fmaf(wq, g4.w, mve[n][3]);
      }
    }
    #pragma unroll
    for (int n = 0; n < 12; ++n) {
      int row = bb * 12 + n;
      ushort4 mp = make_ushort4(f2b(mve[n][0]), f2b(mve[n][1]), f2b(mve[n][2]), f2b(mve[n][3]));
      *(ushort4*)(sm + row * 256 + ((d4 * 2) ^ ((row & 7) << 4))) = mp;
    }
  }
  __syncthreads();

  // VE: X = [ve_g | eout]; dump into s_e (consumed)
  run_pass(wb_ve, sm, se, y_ve, se, 1);

  // block-level stat reduction -> partials
  #pragma unroll
  for (int ni = 0; ni < 4; ++ni) {
    float s1 = sE[ni], q1 = qE[ni], s2 = sV[ni], q2 = qV[ni];
    s1 += __shfl_xor(s1, 16); s1 += __shfl_xor(s1, 32);
    q1 += __shfl_xor(q1, 16); q1 += __shfl_xor(q1, 32);
    s2 += __shfl_xor(s2, 16); s2 += __shfl_xor(s2, 32);
    q2 += __shfl_xor(q2, 16); q2 += __shfl_xor(q2, 32);
    if (l < 16) {
      int ch = (wn * 4 + ni) * 16 + l;
      atomicAdd(&s_red[ch], s1);       atomicAdd(&s_red[128 + ch], q1);
      atomicAdd(&s_red[256 + ch], s2); atomicAdd(&s_red[384 + ch], q2);
    }
  }
  __syncthreads();
  part1[(size_t)blockIdx.x * 512 + tid] = s_red[tid];
  part1[(size_t)blockIdx.x * 512 + 256 + tid] = s_red[256 + tid];
}

// ---------------- fin1: reduce partials -> BN affine for ev/ve ---------------------
__global__ void k_fin1(const float* __restrict__ part1, float* __restrict__ scale,
                       const float* __restrict__ gev, const float* __restrict__ bev,
                       const float* __restrict__ gve, const float* __restrict__ bve)
{
  int t = threadIdx.x;
  int m = t >> 7, d = t & 127;
  float s = 0.f, q = 0.f;
  for (int b = 0; b < 2048; ++b) {
    s += part1[(size_t)b * 512 + m * 256 + d];
    q += part1[(size_t)b * 512 + m * 256 + 128 + d];
  }
  float cnt = (float)(BTOT * 12);
  float mean = s / cnt, var = q / cnt - mean * mean;
  float rs = rsqrtf(var + 1e-5f);
  float g = m ? gve[d] : gev[d];
  float b = m ? bve[d] : bev[d];
  float a = g * rs;
  scale[m * 256 + d] = a;
  scale[m * 256 + 128 + d] = b - mean * a;
}

// ---------------- stage2: grouped MFMA GEMMs for op rows + stat partials -----------
// block: 4 waves, one op-row r = bid&7, 64 batches; M=64, N=128, K=256/384
__global__ __launch_bounds__(256, 2) void k_stage2(
    const u16* __restrict__ y_ev, const u16* __restrict__ y_ve,
    const float* __restrict__ scale,
    const u16* __restrict__ wb1, const u16* __restrict__ wb2,
    const u16* __restrict__ wb3, const u16* __restrict__ wb4,
    u16* __restrict__ y_op, float* __restrict__ part2)
{
  __shared__ __align__(16) u16 s_x[64 * 384];
  __shared__ __align__(16) u16 s_w[128 * 64];
  __shared__ float s_red[256];
  char* sx = (char*)s_x; char* sw = (char*)s_w;

  const int tid = threadIdx.x, l = tid & 63, wv = tid >> 6;
  const int r = blockIdx.x & 7;
  const int b0 = (blockIdx.x >> 3) * 64;
  const int Kr = (r >= 3 && r <= 6) ? 256 : 384;
  const int stK = Kr * 2;
  const int nslots = Kr >> 7;
  const u16* wr = (r == 0) ? wb1 : (r <= 2) ? wb2 : (r <= 6) ? wb3 : wb4;
  s_red[tid] = 0.f;

  // stage X: BN+relu applied from bf16 y -> bf16, swizzled rows (stride Kr*2 B)
  for (int s = 0; s < nslots; ++s) {
    int mb = c_mb[r][s], j = c_mj[r][s];
    const u16* ysrc = mb ? y_ve : y_ev;
    int sb = mb ? 256 : 0;
    #pragma unroll
    for (int q = 0; q < 8; ++q) {
      int i = tid + q * 256;
      int bb = i >> 5, d4 = (i & 31) * 4;
      ushort4 u = *(const ushort4*)&ysrc[((size_t)(b0 + bb) * 12 + j) * 128 + d4];
      float4 a4 = *(const float4*)&scale[sb + d4];
      float4 c4 = *(const float4*)&scale[sb + 128 + d4];
      ushort4 o;
      o.x = f2b(fmaxf(fmaf(b2f(u.x), a4.x, c4.x), 0.f));
      o.y = f2b(fmaxf(fmaf(b2f(u.y), a4.y, c4.y), 0.f));
      o.z = f2b(fmaxf(fmaf(b2f(u.z), a4.z, c4.z), 0.f));
      o.w = f2b(fmaxf(fmaf(b2f(u.w), a4.w, c4.w), 0.f));
      *(ushort4*)(sx + bb * stK + ((s * 256 + d4 * 2) ^ ((bb & 7) << 4))) = o;
    }
  }
  __syncthreads();

  f32x4 acc[8];
  #pragma unroll
  for (int ni = 0; ni < 8; ++ni) acc[ni] = (f32x4){0.f, 0.f, 0.f, 0.f};
  const int nchunks = Kr >> 6;
  for (int c = 0; c < nchunks; ++c) {
    #pragma unroll
    for (int q = 0; q < 4; ++q) {
      int i = tid + q * 256;
      int n = i >> 3, ko = (i & 7) * 8;
      u16x8 w8 = *(const u16x8*)&wr[n * Kr + c * 64 + ko];
      *(u16x8*)(sw + n * 128 + ((ko * 2) ^ ((n & 7) << 4))) = w8;
    }
    __syncthreads();
    #pragma unroll
    for (int kt = 0; kt < 2; ++kt) {
      int row = wv * 16 + (l & 15);
      int kb = ((c * 64 + kt * 32) + ((l >> 4) * 8)) * 2;
      bf16x8 a = *(const bf16x8*)(sx + row * stK + (kb ^ ((row & 7) << 4)));
      int kw = ((kt * 32) + ((l >> 4) * 8)) * 2;
      #pragma unroll
      for (int ni = 0; ni < 8; ++ni) {
        int n = ni * 16 + (l & 15);
        bf16x8 b = *(const bf16x8*)(sw + n * 128 + (kw ^ ((n & 7) << 4)));
        acc[ni] = MFMA16(a, b, acc[ni]);
      }
    }
    __syncthreads();
  }

  // stats + dump (reuse s_x as 64x128 u16, stride 256B)
  #pragma unroll
  for (int ni = 0; ni < 8; ++ni) {
    float s1 = 0.f, q1 = 0.f;
    #pragma unroll
    for (int q = 0; q < 4; ++q) {
      float v = acc[ni][q];
      s1 += v; q1 += v * v;
      int row = wv * 16 + (l >> 4) * 4 + q;
      int cb = (ni * 16 + (l & 15)) * 2;
      *(u16*)(sx + row * 256 + (cb ^ ((row & 7) << 4))) = f2b(v);
    }
    s1 += __shfl_xor(s1, 16); s1 += __shfl_xor(s1, 32);
    q1 += __shfl_xor(q1, 16); q1 += __shfl_xor(q1, 32);
    if (l < 16) {
      int ch = ni * 16 + l;
      atomicAdd(&s_red[ch], s1);
      atomicAdd(&s_red[128 + ch], q1);
    }
  }
  __syncthreads();
  #pragma unroll
  for (int q = 0; q < 4; ++q) {
    int i = tid + q * 256;
    int row = i >> 4, cb = (i & 15) * 16;
    u16x8 v = *(const u16x8*)(sx + row * 256 + (cb ^ ((row & 7) << 4)));
    *(u16x8*)&y_op[((size_t)(b0 + row) * 8 + r) * 128 + (i & 15) * 8] = v;
  }
  part2[(size_t)blockIdx.x * 256 + tid] = s_red[tid];
}

// ---------------- fin2: reduce partials -> BN affine for ops -----------------------
__global__ void k_fin2(const float* __restrict__ part2, float* __restrict__ scale,
    const float* __restrict__ g1, const float* __restrict__ b1,
    const float* __restrict__ g2, const float* __restrict__ b2,
    const float* __restrict__ g3, const float* __restrict__ b3,
    const float* __restrict__ g4, const float* __restrict__ b4)
{
  int t = threadIdx.x; // 512
  int o = t >> 7, d = t & 127;
  int r0 = (o == 0) ? 0 : (o == 1) ? 1 : (o == 2) ? 3 : 7;
  int nr = (o == 0) ? 1 : (o == 1) ? 2 : (o == 2) ? 4 : 1;
  float s = 0.f, q = 0.f;
  for (int rr = r0; rr < r0 + nr; ++rr)
    for (int c = 0; c < 256; ++c) {
      size_t base = ((size_t)c * 8 + rr) * 256;
      s += part2[base + d];
      q += part2[base + 128 + d];
    }
  float cnt = nr * 16384.f;
  float mean = s / cnt, var = q / cnt - mean * mean;
  float rs = rsqrtf(var + 1e-5f);
  const float* gp = (o == 0) ? g1 : (o == 1) ? g2 : (o == 2) ? g3 : g4;
  const float* bp = (o == 0) ? b1 : (o == 1) ? b2 : (o == 2) ? b3 : b4;
  float a = gp[d] * rs;
  scale[512 + o * 256 + d] = a;
  scale[512 + o * 256 + 128 + d] = bp[d] - mean * a;
}

// ---------------- stage3: BN-apply + permute + residual relu -----------------------
__global__ __launch_bounds__(256) void k_stage3(
    const u16* __restrict__ y_op, const u16* __restrict__ y_ve,
    const float* __restrict__ scale, const float* __restrict__ gout,
    float* __restrict__ out)
{
  const int stride = gridDim.x * 256;
  const int total = BTOT * 12 * 32;
  for (int id = blockIdx.x * 256 + threadIdx.x; id < total; id += stride) {
    int b = id / 384;
    int rem = id - b * 384;
    int i = rem >> 5;
    int d4 = (rem & 31) * 4;
    int j = c_jmap[i];
    float4 v;
    if (j < 8) {
      ushort4 u = *(const ushort4*)&y_op[((size_t)b * 8 + j) * 128 + d4];
      int o = c_opof[j];
      float4 a4 = *(const float4*)&scale[512 + o * 256 + d4];
      float4 c4 = *(const float4*)&scale[512 + o * 256 + 128 + d4];
      v.x = fmaf(b2f(u.x), a4.x, c4.x);
      v.y = fmaf(b2f(u.y), a4.y, c4.y);
      v.z = fmaf(b2f(u.z), a4.z, c4.z);
      v.w = fmaf(b2f(u.w), a4.w, c4.w);
    } else {
      int jv = c_vj[j - 8];
      ushort4 u = *(const ushort4*)&y_ve[((size_t)b * 12 + jv) * 128 + d4];
      float4 a4 = *(const float4*)&scale[256 + d4];
      float4 c4 = *(const float4*)&scale[384 + d4];
      v.x = fmaxf(fmaf(b2f(u.x), a4.x, c4.x), 0.f);
      v.y = fmaxf(fmaf(b2f(u.y), a4.y, c4.y), 0.f);
      v.z = fmaxf(fmaf(b2f(u.z), a4.z, c4.z), 0.f);
      v.w = fmaxf(fmaf(b2f(u.w), a4.w, c4.w), 0.f);
    }
    float4 g4 = *(const float4*)&gout[((size_t)b * 12 + i) * 128 + d4];
    float4 r4;
    r4.x = fmaxf(g4.x + v.x, 0.f);
    r4.y = fmaxf(g4.y + v.y, 0.f);
    r4.z = fmaxf(g4.z + v.z, 0.f);
    r4.w = fmaxf(g4.w + v.w, 0.f);
    *(float4*)&out[((size_t)b * 12 + i) * 128 + d4] = r4;
  }
}

extern "C" void kernel_launch(void* const* d_in, const int* in_sizes, int n_in,
                              void* d_out, int out_size, void* d_ws, size_t ws_size,
                              hipStream_t stream) {
  (void)in_sizes; (void)n_in; (void)out_size; (void)ws_size;
  const float* gout = (const float*)d_in[0];
  const float* eout = (const float*)d_in[1];
  const float* evs  = (const float*)d_in[2];
  const float* ves  = (const float*)d_in[3];
  const float* wev  = (const float*)d_in[4];
  const float* wve  = (const float*)d_in[5];
  const float* w1   = (const float*)d_in[6];
  const float* w2   = (const float*)d_in[7];
  const float* w3   = (const float*)d_in[8];
  const float* w4   = (const float*)d_in[9];
  const float* g_ev = (const float*)d_in[10]; const float* b_ev = (const float*)d_in[11];
  const float* g_ve = (const float*)d_in[12]; const float* b_ve = (const float*)d_in[13];
  const float* g_1  = (const float*)d_in[14]; const float* b_1  = (const float*)d_in[15];
  const float* g_2  = (const float*)d_in[16]; const float* b_2  = (const float*)d_in[17];
  const float* g_3  = (const float*)d_in[18]; const float* b_3  = (const float*)d_in[19];
  const float* g_4  = (const float*)d_in[20]; const float* b_4  = (const float*)d_in[21];

  char* ws = (char*)d_ws;
  u16*   y_ev  = (u16*)ws;                      // 50,331,648 B
  u16*   y_ve  = (u16*)(ws + 50331648);         // 50,331,648 B
  u16*   y_op  = (u16*)(ws + 100663296);        // 33,554,432 B
  float* part1 = (float*)(ws + 100663296);      // 4 MB, overlays y_op (consumed before stage2)
  u16*   wb    = (u16*)(ws + 134217728);        // 491,520 B
  float* part2 = (float*)(ws + 134709248);      // 2,097,152 B
  float* scale = (float*)(ws + 136806400);      // 6,144 B

  k_prep<<<960, 256, 0, stream>>>(wev, wve, w1, w2, w3, w4, wb);
  k_stage1<<<2048, 256, 0, stream>>>(gout, eout, evs, ves, wb, wb + 32768, y_ev, y_ve, part1);
  k_fin1<<<1, 256, 0, stream>>>(part1, scale, g_ev, b_ev, g_ve, b_ve);
  k_stage2<<<2048, 256, 0, stream>>>(y_ev, y_ve, scale, wb + 65536, wb + 114688, wb + 163840, wb + 196608, y_op, part2);
  k_fin2<<<1, 512, 0, stream>>>(part2, scale, g_1, b_1, g_2, b_2, g_3, b_3, g_4, b_4);
  k_stage3<<<4096, 256, 0, stream>>>(y_op, y_ve, scale, gout, (float*)d_out);
}